// Round 3
// baseline (420.792 us; speedup 1.0000x reference)
//
#include <hip/hip_runtime.h>
#include <hip/hip_bf16.h>
#include <cstdint>
#include <cstddef>

#define H_DIM 1024
#define I_DIM 512
#define E_NUM 32
#define SHARED_I_DIM 1024
#define TOPK 4
#define NGROUP 8
#define TOPKG 4

typedef __attribute__((ext_vector_type(8))) short bf16x8;
typedef __attribute__((ext_vector_type(4))) float f32x4;
typedef __attribute__((ext_vector_type(8))) unsigned short u16x8;

__device__ inline unsigned short f2bf(float f) {
    __hip_bfloat16 h = __float2bfloat16(f);   // RNE -> v_cvt_pk_bf16_f32
    return *reinterpret_cast<unsigned short*>(&h);
}

// LDS address (in shorts) for [rows][64] bf16 tile, 16B-chunk XOR swizzle.
__device__ inline int laddr(int row, int chunk) {
    return row * 64 + ((chunk ^ (row & 7)) << 3);
}

// ---------------- init: zero cnt + cnt2 ----------------
__global__ void init_kernel(int* cnt) {
    if (threadIdx.x < 64) cnt[threadIdx.x] = 0;
}

// ---------------- fp32 -> bf16 convert (x) ----------------
__global__ void cvt_kernel(const float* __restrict__ src, unsigned short* __restrict__ dst, int n8) {
    int i = blockIdx.x * blockDim.x + threadIdx.x;
    if (i >= n8) return;
    float4 a = *(const float4*)(src + (size_t)i * 8);
    float4 b = *(const float4*)(src + (size_t)i * 8 + 4);
    u16x8 v;
    v[0] = f2bf(a.x); v[1] = f2bf(a.y); v[2] = f2bf(a.z); v[3] = f2bf(a.w);
    v[4] = f2bf(b.x); v[5] = f2bf(b.y); v[6] = f2bf(b.z); v[7] = f2bf(b.w);
    *(u16x8*)(dst + (size_t)i * 8) = v;
}

// ---------------- gating: logits only (fp32 exact) ----------------
__global__ void gate_kernel(const float* __restrict__ x, const float* __restrict__ gw,
                            float* __restrict__ logits_out) {
    int t = blockIdx.x;
    int tid = threadIdx.x;
    int e = tid & 31, part = tid >> 5;            // 8 partial sums over H
    const float* wrow = gw + (size_t)e * H_DIM + part * 128;
    const float* xrow = x + (size_t)t * H_DIM + part * 128;
    float acc = 0.f;
#pragma unroll 8
    for (int h = 0; h < 128; h += 4) {
        float4 a = *(const float4*)(xrow + h);
        float4 b = *(const float4*)(wrow + h);
        acc += a.x * b.x + a.y * b.y + a.z * b.z + a.w * b.w;
    }
    __shared__ float partial[8][32];
    partial[part][e] = acc;
    __syncthreads();
    if (tid < 32) {
        float l = 0.f;
#pragma unroll
        for (int p = 0; p < 8; p++) l += partial[p][tid];
        logits_out[(size_t)t * E_NUM + tid] = l;
    }
}

// ---------------- selection: per-token thread, register-only ----------------
__global__ void select_kernel(const float* __restrict__ logits, const float* __restrict__ gb,
                              int* __restrict__ topk_e, float* __restrict__ topk_w,
                              int* __restrict__ cnt, int T) {
    int t = blockIdx.x * blockDim.x + threadIdx.x;
    if (t >= T) return;
    float scores[E_NUM], sfc[E_NUM];
#pragma unroll
    for (int i = 0; i < E_NUM; i++) {
        float l = logits[(size_t)t * E_NUM + i];
        float s = 1.f / (1.f + expf(-l));
        scores[i] = s;
        sfc[i] = s + gb[i];
    }
    float gs[NGROUP];
#pragma unroll
    for (int g = 0; g < NGROUP; g++) {
        float m1 = -1e30f, m2 = -1e30f;
#pragma unroll
        for (int j = 0; j < 4; j++) {
            float v = sfc[g * 4 + j];
            if (v > m1) { m2 = m1; m1 = v; }
            else if (v > m2) { m2 = v; }
        }
        gs[g] = m1 + m2;
    }
    unsigned gmask = 0;
    for (int r = 0; r < TOPKG; r++) {
        int best = 0; float bv = -1e30f;
#pragma unroll
        for (int g = 0; g < NGROUP; g++)
            if (!((gmask >> g) & 1u) && gs[g] > bv) { bv = gs[g]; best = g; }
        gmask |= 1u << best;
    }
    unsigned cmask = 0;
    int eidx[TOPK]; float ew[TOPK]; float sum = 0.f;
    for (int r = 0; r < TOPK; r++) {
        int best = 0; float bv = -1e30f; float bsc = 0.f;
#pragma unroll
        for (int i = 0; i < E_NUM; i++) {
            float v = ((gmask >> (i >> 2)) & 1u) ? sfc[i] : 0.0f;
            if (!((cmask >> i) & 1u) && v > bv) { bv = v; best = i; bsc = scores[i]; }
        }
        cmask |= 1u << best;
        eidx[r] = best; ew[r] = bsc; sum += bsc;
    }
    float inv = 1.f / (sum + 1e-20f);
#pragma unroll
    for (int k = 0; k < TOPK; k++) {
        topk_e[t * TOPK + k] = eidx[k];
        topk_w[t * TOPK + k] = ew[k] * inv;   // SCALE = 1
        atomicAdd(&cnt[eidx[k]], 1);
    }
}

// ---------------- scan: offsets ----------------
__global__ void scan_kernel(const int* __restrict__ cnt, int* __restrict__ off) {
    if (threadIdx.x == 0) {
        int a = 0;
        for (int e = 0; e < E_NUM; e++) { off[e] = a; a += cnt[e]; }
        off[E_NUM] = a;
    }
}

// ---------------- bin: token -> expert slots ----------------
__global__ void bin_kernel(const int* __restrict__ topk_e, const float* __restrict__ topk_w,
                           const int* __restrict__ off, int* __restrict__ cnt2,
                           int* __restrict__ slot_token, float* __restrict__ slot_w, int total) {
    int i = blockIdx.x * blockDim.x + threadIdx.x;
    if (i >= total) return;
    int e = topk_e[i];
    float w = topk_w[i];
    int pos = atomicAdd(&cnt2[e], 1);
    int slot = off[e] + pos;
    slot_token[slot] = i >> 2;
    slot_w[slot] = w;
}

// ---------------- BM x 64 MFMA GEMM, BK=64, A bf16, B fp32 ----------------
// MODE 0: dst = bf16( silu(g)*u*w )   (DUAL must be true)
// MODE 1: dst(float) = acc            (plain store)
// MODE 2: atomicAdd(out[token], acc)  (routed scatter)
template <int MODE, bool DUAL, int BM, bool ROUTED, bool AGATHER>
__global__ __launch_bounds__(256, 1) void gemm_kernel(
    const unsigned short* __restrict__ A, const float* __restrict__ B1,
    const float* __restrict__ B2, size_t bstride,
    void* __restrict__ Dst, int ldD,
    const int* __restrict__ slot_token, const float* __restrict__ slot_w,
    const int* __restrict__ cnt, const int* __restrict__ off_arr, int K, int Mtot) {
    static_assert(MODE != 0 || DUAL, "MODE0 requires DUAL");
    constexpr int NP = BM / 64;     // A staging passes
    constexpr int RW = BM / 4;      // rows per wave
    constexpr int MF = RW / 16;     // m-frags per wave

    int itile = blockIdx.x, mtile = blockIdx.y;
    int e = ROUTED ? blockIdx.z : 0;
    int count = Mtot, base = 0;
    if (ROUTED) {
        count = cnt[e];
        base = off_arr[e];
        if (mtile * BM >= count) return;
    }

    __shared__ __align__(16) unsigned short As[BM * 64];
    __shared__ __align__(16) unsigned short Bs1[64 * 64];
    __shared__ __align__(16) unsigned short Bs2[DUAL ? 64 * 64 : 8];

    int tid = threadIdx.x;
    int cg = tid & 3;               // 16-col group

    const unsigned short* Arow[NP];
#pragma unroll
    for (int p = 0; p < NP; p++) {
        int am = mtile * BM + p * 64 + (tid >> 2);
        int ar;
        if (AGATHER)      ar = (am < count) ? slot_token[base + am] : 0;
        else if (ROUTED)  ar = base + ((am < count) ? am : 0);
        else              ar = (am < count) ? am : 0;
        Arow[p] = A + (size_t)ar * K;
    }

    int brow = itile * 64 + (tid >> 2);
    const float* B1r = B1 + (size_t)e * bstride + (size_t)brow * K;
    const float* B2r = DUAL ? (B2 + (size_t)e * bstride + (size_t)brow * K) : nullptr;

    f32x4 acc1[MF][4] = {};
    f32x4 acc2[DUAL ? MF : 1][4] = {};

    int lane = tid & 63, wid = tid >> 6;
    int frow = lane & 15, fchunk = lane >> 4;
    int wrow = wid * RW;

    for (int k0 = 0; k0 < K; k0 += 64) {
        __syncthreads();
        // stage A (bf16 copy)
#pragma unroll
        for (int p = 0; p < NP; p++) {
            int r = p * 64 + (tid >> 2);
            u16x8 v0 = *(const u16x8*)(Arow[p] + k0 + cg * 16);
            u16x8 v1 = *(const u16x8*)(Arow[p] + k0 + cg * 16 + 8);
            *(u16x8*)(&As[laddr(r, cg * 2)]) = v0;
            *(u16x8*)(&As[laddr(r, cg * 2 + 1)]) = v1;
        }
        // stage B1 (fp32 -> bf16)
        {
            int r = tid >> 2;
            float4 b0 = *(const float4*)(B1r + k0 + cg * 16);
            float4 b1 = *(const float4*)(B1r + k0 + cg * 16 + 4);
            float4 b2 = *(const float4*)(B1r + k0 + cg * 16 + 8);
            float4 b3 = *(const float4*)(B1r + k0 + cg * 16 + 12);
            u16x8 s0, s1;
            s0[0] = f2bf(b0.x); s0[1] = f2bf(b0.y); s0[2] = f2bf(b0.z); s0[3] = f2bf(b0.w);
            s0[4] = f2bf(b1.x); s0[5] = f2bf(b1.y); s0[6] = f2bf(b1.z); s0[7] = f2bf(b1.w);
            s1[0] = f2bf(b2.x); s1[1] = f2bf(b2.y); s1[2] = f2bf(b2.z); s1[3] = f2bf(b2.w);
            s1[4] = f2bf(b3.x); s1[5] = f2bf(b3.y); s1[6] = f2bf(b3.z); s1[7] = f2bf(b3.w);
            *(u16x8*)(&Bs1[laddr(r, cg * 2)]) = s0;
            *(u16x8*)(&Bs1[laddr(r, cg * 2 + 1)]) = s1;
        }
        if constexpr (DUAL) {
            int r = tid >> 2;
            float4 b0 = *(const float4*)(B2r + k0 + cg * 16);
            float4 b1 = *(const float4*)(B2r + k0 + cg * 16 + 4);
            float4 b2 = *(const float4*)(B2r + k0 + cg * 16 + 8);
            float4 b3 = *(const float4*)(B2r + k0 + cg * 16 + 12);
            u16x8 s0, s1;
            s0[0] = f2bf(b0.x); s0[1] = f2bf(b0.y); s0[2] = f2bf(b0.z); s0[3] = f2bf(b0.w);
            s0[4] = f2bf(b1.x); s0[5] = f2bf(b1.y); s0[6] = f2bf(b1.z); s0[7] = f2bf(b1.w);
            s1[0] = f2bf(b2.x); s1[1] = f2bf(b2.y); s1[2] = f2bf(b2.z); s1[3] = f2bf(b2.w);
            s1[4] = f2bf(b3.x); s1[5] = f2bf(b3.y); s1[6] = f2bf(b3.z); s1[7] = f2bf(b3.w);
            *(u16x8*)(&Bs2[laddr(r, cg * 2)]) = s0;
            *(u16x8*)(&Bs2[laddr(r, cg * 2 + 1)]) = s1;
        }
        __syncthreads();
#pragma unroll
        for (int kk = 0; kk < 2; kk++) {
            int cb = fchunk + kk * 4;
            bf16x8 afr[MF], bfr1[4], bfr2[DUAL ? 4 : 1];
#pragma unroll
            for (int nf = 0; nf < 4; nf++)
                bfr1[nf] = *(const bf16x8*)(&Bs1[laddr(nf * 16 + frow, cb)]);
            if constexpr (DUAL) {
#pragma unroll
                for (int nf = 0; nf < 4; nf++)
                    bfr2[nf] = *(const bf16x8*)(&Bs2[laddr(nf * 16 + frow, cb)]);
            }
#pragma unroll
            for (int mf = 0; mf < MF; mf++)
                afr[mf] = *(const bf16x8*)(&As[laddr(wrow + mf * 16 + frow, cb)]);
#pragma unroll
            for (int mf = 0; mf < MF; mf++)
#pragma unroll
                for (int nf = 0; nf < 4; nf++) {
                    acc1[mf][nf] = __builtin_amdgcn_mfma_f32_16x16x32_bf16(afr[mf], bfr1[nf], acc1[mf][nf], 0, 0, 0);
                    if constexpr (DUAL)
                        acc2[mf][nf] = __builtin_amdgcn_mfma_f32_16x16x32_bf16(afr[mf], bfr2[nf], acc2[mf][nf], 0, 0, 0);
                }
        }
    }

    // ---- epilogue ----
#pragma unroll
    for (int mf = 0; mf < MF; mf++)
#pragma unroll
        for (int nf = 0; nf < 4; nf++)
#pragma unroll
            for (int j = 0; j < 4; j++) {
                int rloc = wrow + mf * 16 + (lane >> 4) * 4 + j;
                int mrow = mtile * BM + rloc;
                int col = itile * 64 + nf * 16 + (lane & 15);
                if (mrow >= count) continue;
                if constexpr (MODE == 0) {
                    float w = ROUTED ? slot_w[base + mrow] : 1.0f;
                    float g = acc1[mf][nf][j];
                    float a = (g / (1.f + __expf(-g))) * acc2[mf][nf][j] * w;
                    ((unsigned short*)Dst)[(size_t)(base + mrow) * ldD + col] = f2bf(a);
                } else if constexpr (MODE == 1) {
                    ((float*)Dst)[(size_t)mrow * ldD + col] = acc1[mf][nf][j];
                } else {
                    int tok = slot_token[base + mrow];
                    atomicAdd(((float*)Dst) + (size_t)tok * ldD + col, acc1[mf][nf][j]);
                }
            }
}

extern "C" void kernel_launch(void* const* d_in, const int* in_sizes, int n_in,
                              void* d_out, int out_size, void* d_ws, size_t ws_size,
                              hipStream_t stream) {
    const float* x = (const float*)d_in[0];
    const float* gw = (const float*)d_in[1];
    const float* gb = (const float*)d_in[2];
    const float* gate_proj = (const float*)d_in[3];
    const float* up_proj = (const float*)d_in[4];
    const float* down_proj = (const float*)d_in[5];
    const float* sgw = (const float*)d_in[6];
    const float* suw = (const float*)d_in[7];
    const float* sdw = (const float*)d_in[8];
    float* out = (float*)d_out;

    const int T = in_sizes[0] / H_DIM;       // 2048
    const int total_slots = T * TOPK;        // 8192

    char* ws = (char*)d_ws;
    int* cnt = (int*)ws;                     // 32
    int* cnt2 = cnt + 32;                    // 32
    int* off = cnt + 64;                     // 33
    int* topk_e = cnt + 128;
    float* topk_w = (float*)(topk_e + total_slots);
    int* slot_token = (int*)(topk_w + total_slots);
    float* slot_w = (float*)(slot_token + total_slots);
    float* logits = slot_w + total_slots;                         // T*32 f32
    unsigned short* x_bf = (unsigned short*)(logits + (size_t)T * E_NUM);
    unsigned short* act_r = x_bf + (size_t)T * H_DIM;             // (slots+256) x I
    unsigned short* act_s = act_r + (size_t)(total_slots + 256) * I_DIM;  // T x SHARED_I

    hipLaunchKernelGGL(init_kernel, dim3(1), dim3(64), 0, stream, cnt);
    hipLaunchKernelGGL(cvt_kernel, dim3((T * H_DIM / 8 + 255) / 256), dim3(256), 0, stream,
                       x, x_bf, T * H_DIM / 8);
    hipLaunchKernelGGL(gate_kernel, dim3(T), dim3(256), 0, stream, x, gw, logits);
    hipLaunchKernelGGL(select_kernel, dim3((T + 255) / 256), dim3(256), 0, stream,
                       logits, gb, topk_e, topk_w, cnt, T);
    hipLaunchKernelGGL(scan_kernel, dim3(1), dim3(1), 0, stream, cnt, off);
    hipLaunchKernelGGL(bin_kernel, dim3((total_slots + 255) / 256), dim3(256), 0, stream,
                       topk_e, topk_w, off, cnt2, slot_token, slot_w, total_slots);

    // routed stage 1: act_r = bf16(silu(x@gateT)*(x@upT)*w), BM=256 -> weights read once
    hipLaunchKernelGGL((gemm_kernel<0, true, 256, true, true>),
                       dim3(I_DIM / 64, 32, E_NUM), dim3(256), 0, stream,
                       x_bf, gate_proj, up_proj, (size_t)I_DIM * H_DIM,
                       (void*)act_r, I_DIM, slot_token, slot_w, cnt, off, H_DIM, 0);

    // shared stage 1: BM=128
    hipLaunchKernelGGL((gemm_kernel<0, true, 128, false, false>),
                       dim3(SHARED_I_DIM / 64, T / 128, 1), dim3(256), 0, stream,
                       x_bf, sgw, suw, (size_t)0,
                       (void*)act_s, SHARED_I_DIM, (const int*)nullptr, (const float*)nullptr,
                       (const int*)nullptr, (const int*)nullptr, H_DIM, T);

    // shared down: plain fp32 store (covers every (t,h) once)
    hipLaunchKernelGGL((gemm_kernel<1, false, 128, false, false>),
                       dim3(H_DIM / 64, T / 128, 1), dim3(256), 0, stream,
                       act_s, sdw, (const float*)nullptr, (size_t)0,
                       (void*)out, H_DIM, (const int*)nullptr, (const float*)nullptr,
                       (const int*)nullptr, (const int*)nullptr, SHARED_I_DIM, T);

    // routed down: atomicAdd scatter onto shared result, BM=256 -> down weights read once
    hipLaunchKernelGGL((gemm_kernel<2, false, 256, true, false>),
                       dim3(H_DIM / 64, 32, E_NUM), dim3(256), 0, stream,
                       act_r, down_proj, (const float*)nullptr, (size_t)H_DIM * I_DIM,
                       (void*)out, H_DIM, slot_token, (const float*)nullptr, cnt, off, I_DIM, 0);
}

// Round 4
// 313.768 us; speedup vs baseline: 1.3411x; 1.3411x over previous
//
#include <hip/hip_runtime.h>
#include <hip/hip_bf16.h>
#include <cstdint>
#include <cstddef>

#define H_DIM 1024
#define I_DIM 512
#define E_NUM 32
#define SHARED_I_DIM 1024
#define TOPK 4
#define NGROUP 8
#define TOPKG 4
#define GT 8   // tokens per gate block

typedef __attribute__((ext_vector_type(8))) short bf16x8;
typedef __attribute__((ext_vector_type(4))) float f32x4;
typedef __attribute__((ext_vector_type(8))) unsigned short u16x8;

__device__ inline unsigned short f2bf(float f) {
    __hip_bfloat16 h = __float2bfloat16(f);   // RNE -> v_cvt_pk_bf16_f32
    return *reinterpret_cast<unsigned short*>(&h);
}

// LDS address (in shorts) for [rows][64] bf16 tile, 16B-chunk XOR swizzle.
__device__ inline int laddr(int row, int chunk) {
    return row * 64 + ((chunk ^ (row & 7)) << 3);
}

// ---------------- init: zero cnt + cnt2 ----------------
__global__ void init_kernel(int* cnt) {
    if (threadIdx.x < 64) cnt[threadIdx.x] = 0;
}

// ---------------- fp32 -> bf16 convert (x) ----------------
__global__ void cvt_kernel(const float* __restrict__ src, unsigned short* __restrict__ dst, int n8) {
    int i = blockIdx.x * blockDim.x + threadIdx.x;
    if (i >= n8) return;
    float4 a = *(const float4*)(src + (size_t)i * 8);
    float4 b = *(const float4*)(src + (size_t)i * 8 + 4);
    u16x8 v;
    v[0] = f2bf(a.x); v[1] = f2bf(a.y); v[2] = f2bf(a.z); v[3] = f2bf(a.w);
    v[4] = f2bf(b.x); v[5] = f2bf(b.y); v[6] = f2bf(b.z); v[7] = f2bf(b.w);
    *(u16x8*)(dst + (size_t)i * 8) = v;
}

// ---------------- gating: 8 tokens per block, fp32 exact ----------------
__global__ __launch_bounds__(256) void gate_kernel(const float* __restrict__ x,
                                                   const float* __restrict__ gw,
                                                   float* __restrict__ logits_out) {
    int tb = blockIdx.x;
    int tid = threadIdx.x;
    __shared__ float xs[GT][H_DIM];          // 32 KB
    __shared__ float ps[8][GT][E_NUM];       // 8 KB
    const float* xsrc = x + (size_t)tb * GT * H_DIM;
    for (int i = tid; i < GT * H_DIM / 4; i += 256)
        ((float4*)&xs[0][0])[i] = ((const float4*)xsrc)[i];
    __syncthreads();
    int e = tid & 31, part = tid >> 5;       // 8 parts x 128 cols
    const float* wrow = gw + (size_t)e * H_DIM + part * 128;
    float acc[GT] = {};
    for (int c0 = 0; c0 < 128; c0 += 32) {
        float w[32];
#pragma unroll
        for (int c = 0; c < 32; c++) w[c] = wrow[c0 + c];
#pragma unroll
        for (int t = 0; t < GT; t++) {
#pragma unroll
            for (int c = 0; c < 32; c++)
                acc[t] += w[c] * xs[t][part * 128 + c0 + c];
        }
    }
#pragma unroll
    for (int t = 0; t < GT; t++) ps[part][t][e] = acc[t];
    __syncthreads();
    {
        int t = tid >> 5, ee = tid & 31;     // 8*32 = 256 exact
        float s = 0.f;
#pragma unroll
        for (int p = 0; p < 8; p++) s += ps[p][t][ee];
        logits_out[((size_t)tb * GT + t) * E_NUM + ee] = s;
    }
}

// ---------------- selection: per-token thread, register-only ----------------
__global__ void select_kernel(const float* __restrict__ logits, const float* __restrict__ gb,
                              int* __restrict__ topk_e, float* __restrict__ topk_w,
                              int* __restrict__ cnt, int T) {
    int t = blockIdx.x * blockDim.x + threadIdx.x;
    if (t >= T) return;
    float scores[E_NUM], sfc[E_NUM];
#pragma unroll
    for (int i = 0; i < E_NUM; i++) {
        float l = logits[(size_t)t * E_NUM + i];
        float s = 1.f / (1.f + expf(-l));
        scores[i] = s;
        sfc[i] = s + gb[i];
    }
    float gs[NGROUP];
#pragma unroll
    for (int g = 0; g < NGROUP; g++) {
        float m1 = -1e30f, m2 = -1e30f;
#pragma unroll
        for (int j = 0; j < 4; j++) {
            float v = sfc[g * 4 + j];
            if (v > m1) { m2 = m1; m1 = v; }
            else if (v > m2) { m2 = v; }
        }
        gs[g] = m1 + m2;
    }
    unsigned gmask = 0;
    for (int r = 0; r < TOPKG; r++) {
        int best = 0; float bv = -1e30f;
#pragma unroll
        for (int g = 0; g < NGROUP; g++)
            if (!((gmask >> g) & 1u) && gs[g] > bv) { bv = gs[g]; best = g; }
        gmask |= 1u << best;
    }
    unsigned cmask = 0;
    int eidx[TOPK]; float ew[TOPK]; float sum = 0.f;
    for (int r = 0; r < TOPK; r++) {
        int best = 0; float bv = -1e30f; float bsc = 0.f;
#pragma unroll
        for (int i = 0; i < E_NUM; i++) {
            float v = ((gmask >> (i >> 2)) & 1u) ? sfc[i] : 0.0f;
            if (!((cmask >> i) & 1u) && v > bv) { bv = v; best = i; bsc = scores[i]; }
        }
        cmask |= 1u << best;
        eidx[r] = best; ew[r] = bsc; sum += bsc;
    }
    float inv = 1.f / (sum + 1e-20f);
#pragma unroll
    for (int k = 0; k < TOPK; k++) {
        topk_e[t * TOPK + k] = eidx[k];
        topk_w[t * TOPK + k] = ew[k] * inv;   // SCALE = 1
        atomicAdd(&cnt[eidx[k]], 1);
    }
}

// ---------------- scan: offsets ----------------
__global__ void scan_kernel(const int* __restrict__ cnt, int* __restrict__ off) {
    if (threadIdx.x == 0) {
        int a = 0;
        for (int e = 0; e < E_NUM; e++) { off[e] = a; a += cnt[e]; }
        off[E_NUM] = a;
    }
}

// ---------------- bin: token -> expert slots ----------------
__global__ void bin_kernel(const int* __restrict__ topk_e, const float* __restrict__ topk_w,
                           const int* __restrict__ off, int* __restrict__ cnt2,
                           int* __restrict__ slot_token, float* __restrict__ slot_w, int total) {
    int i = blockIdx.x * blockDim.x + threadIdx.x;
    if (i >= total) return;
    int e = topk_e[i];
    float w = topk_w[i];
    int pos = atomicAdd(&cnt2[e], 1);
    int slot = off[e] + pos;
    slot_token[slot] = i >> 2;
    slot_w[slot] = w;
}

// ---------------- BM x 64 MFMA GEMM, 512 threads, BK=64, reg-prefetch ----------------
// A bf16, B fp32 (converted in-reg). 8 waves: 4 wave-rows x 2 wave-cols.
// MODE 0: dst = bf16( silu(g)*u*w )   (DUAL must be true)
// MODE 1: dst(float) = acc            (plain store)
// MODE 2: atomicAdd(out[token], acc)  (routed scatter)
template <int MODE, bool DUAL, int BM, bool ROUTED, bool AGATHER>
__global__ __launch_bounds__(512, 2) void gemm_kernel(
    const unsigned short* __restrict__ A, const float* __restrict__ B1,
    const float* __restrict__ B2, size_t bstride,
    void* __restrict__ Dst, int ldD,
    const int* __restrict__ slot_token, const float* __restrict__ slot_w,
    const int* __restrict__ cnt, const int* __restrict__ off_arr, int K, int Mtot) {
    static_assert(MODE != 0 || DUAL, "MODE0 requires DUAL");
    constexpr int RW = BM / 4;        // rows per wave-row
    constexpr int MF = RW / 16;       // m-frags per wave
    constexpr int ACH = BM / 64;      // A 16B-chunks per thread
    constexpr int TPR = 512 / BM;     // threads per A row

    int itile = blockIdx.x, mtile = blockIdx.y;
    int e = ROUTED ? blockIdx.z : 0;
    int count = Mtot, base = 0;
    if (ROUTED) {
        count = cnt[e];
        base = off_arr[e];
        if (mtile * BM >= count) return;
    }

    __shared__ __align__(16) unsigned short As[BM * 64];
    __shared__ __align__(16) unsigned short Bs1[64 * 64];
    __shared__ __align__(16) unsigned short Bs2[DUAL ? 64 * 64 : 8];

    int tid = threadIdx.x;

    // A staging: one row per thread, ACH chunks
    int as_row = tid / TPR;
    int as_cb = (tid % TPR) * ACH;
    int am = mtile * BM + as_row;
    int ar;
    if (AGATHER)      ar = (am < count) ? slot_token[base + am] : 0;
    else if (ROUTED)  ar = base + ((am < count) ? am : 0);
    else              ar = (am < count) ? am : 0;
    const unsigned short* Arow = A + (size_t)ar * K + as_cb * 8;

    // B staging: row = tid>>3, chunk = tid&7 (8 floats each)
    int bs_row = tid >> 3, bs_ch = tid & 7;
    const float* B1r = B1 + (size_t)e * bstride + (size_t)(itile * 64 + bs_row) * K + bs_ch * 8;
    const float* B2r = DUAL ? (B2 + (size_t)e * bstride + (size_t)(itile * 64 + bs_row) * K + bs_ch * 8)
                            : nullptr;

    f32x4 acc1[MF][2] = {};
    f32x4 acc2[DUAL ? MF : 1][2] = {};

    int lane = tid & 63, wid = tid >> 6;
    int wrow = (wid >> 1) * RW, wcol = (wid & 1) * 32;
    int frow = lane & 15, fch = lane >> 4;

    // prefetch register sets (ping-pong, all statically indexed)
    u16x8 pA0[ACH], pA1[ACH];
    float4 b1lo0, b1hi0, b1lo1, b1hi1;
    float4 b2lo0, b2hi0, b2lo1, b2hi1;

    auto loadS = [&](u16x8* pA, float4& b1lo, float4& b1hi, float4& b2lo, float4& b2hi, int k0) {
#pragma unroll
        for (int c = 0; c < ACH; c++) pA[c] = *(const u16x8*)(Arow + k0 + c * 8);
        b1lo = *(const float4*)(B1r + k0);
        b1hi = *(const float4*)(B1r + k0 + 4);
        if constexpr (DUAL) {
            b2lo = *(const float4*)(B2r + k0);
            b2hi = *(const float4*)(B2r + k0 + 4);
        }
    };
    auto writeS = [&](const u16x8* pA, float4 b1lo, float4 b1hi, float4 b2lo, float4 b2hi) {
#pragma unroll
        for (int c = 0; c < ACH; c++)
            *(u16x8*)(&As[laddr(as_row, as_cb + c)]) = pA[c];
        u16x8 s;
        s[0] = f2bf(b1lo.x); s[1] = f2bf(b1lo.y); s[2] = f2bf(b1lo.z); s[3] = f2bf(b1lo.w);
        s[4] = f2bf(b1hi.x); s[5] = f2bf(b1hi.y); s[6] = f2bf(b1hi.z); s[7] = f2bf(b1hi.w);
        *(u16x8*)(&Bs1[laddr(bs_row, bs_ch)]) = s;
        if constexpr (DUAL) {
            u16x8 s2;
            s2[0] = f2bf(b2lo.x); s2[1] = f2bf(b2lo.y); s2[2] = f2bf(b2lo.z); s2[3] = f2bf(b2lo.w);
            s2[4] = f2bf(b2hi.x); s2[5] = f2bf(b2hi.y); s2[6] = f2bf(b2hi.z); s2[7] = f2bf(b2hi.w);
            *(u16x8*)(&Bs2[laddr(bs_row, bs_ch)]) = s2;
        }
    };
    auto compute = [&]() {
#pragma unroll
        for (int kk = 0; kk < 2; kk++) {
            int cb = fch + kk * 4;
            bf16x8 bf1[2], bf2[DUAL ? 2 : 1], af[MF];
#pragma unroll
            for (int nf = 0; nf < 2; nf++)
                bf1[nf] = *(const bf16x8*)(&Bs1[laddr(wcol + nf * 16 + frow, cb)]);
            if constexpr (DUAL) {
#pragma unroll
                for (int nf = 0; nf < 2; nf++)
                    bf2[nf] = *(const bf16x8*)(&Bs2[laddr(wcol + nf * 16 + frow, cb)]);
            }
#pragma unroll
            for (int mf = 0; mf < MF; mf++)
                af[mf] = *(const bf16x8*)(&As[laddr(wrow + mf * 16 + frow, cb)]);
#pragma unroll
            for (int mf = 0; mf < MF; mf++)
#pragma unroll
                for (int nf = 0; nf < 2; nf++) {
                    acc1[mf][nf] = __builtin_amdgcn_mfma_f32_16x16x32_bf16(af[mf], bf1[nf], acc1[mf][nf], 0, 0, 0);
                    if constexpr (DUAL)
                        acc2[mf][nf] = __builtin_amdgcn_mfma_f32_16x16x32_bf16(af[mf], bf2[nf], acc2[mf][nf], 0, 0, 0);
                }
        }
    };

    const int NK = K >> 6;   // even for all uses (16, 16, 16, 8)
    loadS(pA0, b1lo0, b1hi0, b2lo0, b2hi0, 0);
    for (int it = 0; it < NK; it += 2) {
        __syncthreads();                       // prev compute done reading LDS
        writeS(pA0, b1lo0, b1hi0, b2lo0, b2hi0);   // regs loaded 1 iter ago: no stall
        __syncthreads();                       // LDS ready
        loadS(pA1, b1lo1, b1hi1, b2lo1, b2hi1, (it + 1) << 6);  // in flight under compute
        compute();
        __syncthreads();
        writeS(pA1, b1lo1, b1hi1, b2lo1, b2hi1);
        __syncthreads();
        if (it + 2 < NK) loadS(pA0, b1lo0, b1hi0, b2lo0, b2hi0, (it + 2) << 6);
        compute();
    }

    // ---- epilogue ----
#pragma unroll
    for (int mf = 0; mf < MF; mf++)
#pragma unroll
        for (int nf = 0; nf < 2; nf++)
#pragma unroll
            for (int j = 0; j < 4; j++) {
                int rloc = wrow + mf * 16 + (lane >> 4) * 4 + j;
                int mrow = mtile * BM + rloc;
                int col = itile * 64 + wcol + nf * 16 + (lane & 15);
                if (mrow >= count) continue;
                if constexpr (MODE == 0) {
                    float w = ROUTED ? slot_w[base + mrow] : 1.0f;
                    float g = acc1[mf][nf][j];
                    float a = (g / (1.f + __expf(-g))) * acc2[mf][nf][j] * w;
                    ((unsigned short*)Dst)[(size_t)(base + mrow) * ldD + col] = f2bf(a);
                } else if constexpr (MODE == 1) {
                    ((float*)Dst)[(size_t)mrow * ldD + col] = acc1[mf][nf][j];
                } else {
                    int tok = slot_token[base + mrow];
                    atomicAdd(((float*)Dst) + (size_t)tok * ldD + col, acc1[mf][nf][j]);
                }
            }
}

extern "C" void kernel_launch(void* const* d_in, const int* in_sizes, int n_in,
                              void* d_out, int out_size, void* d_ws, size_t ws_size,
                              hipStream_t stream) {
    const float* x = (const float*)d_in[0];
    const float* gw = (const float*)d_in[1];
    const float* gb = (const float*)d_in[2];
    const float* gate_proj = (const float*)d_in[3];
    const float* up_proj = (const float*)d_in[4];
    const float* down_proj = (const float*)d_in[5];
    const float* sgw = (const float*)d_in[6];
    const float* suw = (const float*)d_in[7];
    const float* sdw = (const float*)d_in[8];
    float* out = (float*)d_out;

    const int T = in_sizes[0] / H_DIM;       // 2048
    const int total_slots = T * TOPK;        // 8192

    char* ws = (char*)d_ws;
    int* cnt = (int*)ws;                     // 32
    int* cnt2 = cnt + 32;                    // 32
    int* off = cnt + 64;                     // 33
    int* topk_e = cnt + 128;
    float* topk_w = (float*)(topk_e + total_slots);
    int* slot_token = (int*)(topk_w + total_slots);
    float* slot_w = (float*)(slot_token + total_slots);
    float* logits = slot_w + total_slots;                         // T*32 f32
    unsigned short* x_bf = (unsigned short*)(logits + (size_t)T * E_NUM);
    unsigned short* act_r = x_bf + (size_t)T * H_DIM;             // (slots+256) x I
    unsigned short* act_s = act_r + (size_t)(total_slots + 256) * I_DIM;  // T x SHARED_I

    hipLaunchKernelGGL(init_kernel, dim3(1), dim3(64), 0, stream, cnt);
    hipLaunchKernelGGL(cvt_kernel, dim3((T * H_DIM / 8 + 255) / 256), dim3(256), 0, stream,
                       x, x_bf, T * H_DIM / 8);
    hipLaunchKernelGGL(gate_kernel, dim3(T / GT), dim3(256), 0, stream, x, gw, logits);
    hipLaunchKernelGGL(select_kernel, dim3((T + 255) / 256), dim3(256), 0, stream,
                       logits, gb, topk_e, topk_w, cnt, T);
    hipLaunchKernelGGL(scan_kernel, dim3(1), dim3(1), 0, stream, cnt, off);
    hipLaunchKernelGGL(bin_kernel, dim3((total_slots + 255) / 256), dim3(256), 0, stream,
                       topk_e, topk_w, off, cnt2, slot_token, slot_w, total_slots);

    // routed stage 1: BM=256 (weights read once), 512 threads, reg-prefetch
    hipLaunchKernelGGL((gemm_kernel<0, true, 256, true, true>),
                       dim3(I_DIM / 64, 32, E_NUM), dim3(512), 0, stream,
                       x_bf, gate_proj, up_proj, (size_t)I_DIM * H_DIM,
                       (void*)act_r, I_DIM, slot_token, slot_w, cnt, off, H_DIM, 0);

    // shared stage 1: BM=128, 256 balanced blocks
    hipLaunchKernelGGL((gemm_kernel<0, true, 128, false, false>),
                       dim3(SHARED_I_DIM / 64, T / 128, 1), dim3(512), 0, stream,
                       x_bf, sgw, suw, (size_t)0,
                       (void*)act_s, SHARED_I_DIM, (const int*)nullptr, (const float*)nullptr,
                       (const int*)nullptr, (const int*)nullptr, H_DIM, T);

    // shared down: plain fp32 store (covers every (t,h) once)
    hipLaunchKernelGGL((gemm_kernel<1, false, 128, false, false>),
                       dim3(H_DIM / 64, T / 128, 1), dim3(512), 0, stream,
                       act_s, sdw, (const float*)nullptr, (size_t)0,
                       (void*)out, H_DIM, (const int*)nullptr, (const float*)nullptr,
                       (const int*)nullptr, (const int*)nullptr, SHARED_I_DIM, T);

    // routed down: BM=256, atomicAdd scatter onto shared result
    hipLaunchKernelGGL((gemm_kernel<2, false, 256, true, false>),
                       dim3(H_DIM / 64, 32, E_NUM), dim3(512), 0, stream,
                       act_r, down_proj, (const float*)nullptr, (size_t)H_DIM * I_DIM,
                       (void*)out, H_DIM, slot_token, (const float*)nullptr, cnt, off, I_DIM, 0);
}

// Round 5
// 229.539 us; speedup vs baseline: 1.8332x; 1.3669x over previous
//
#include <hip/hip_runtime.h>
#include <hip/hip_bf16.h>
#include <cstdint>
#include <cstddef>

#define H_DIM 1024
#define I_DIM 512
#define E_NUM 32
#define SHARED_I_DIM 1024
#define TOPK 4
#define NGROUP 8
#define TOPKG 4
#define GT 8   // tokens per gate block

typedef __attribute__((ext_vector_type(8))) short bf16x8;
typedef __attribute__((ext_vector_type(4))) float f32x4;
typedef __attribute__((ext_vector_type(8))) unsigned short u16x8;

__device__ inline unsigned short f2bf(float f) {
    __hip_bfloat16 h = __float2bfloat16(f);   // RNE -> v_cvt_pk_bf16_f32
    return *reinterpret_cast<unsigned short*>(&h);
}

// LDS address (in shorts) for [rows][64] bf16 tile, 16B-chunk XOR swizzle.
__device__ inline int laddr(int row, int chunk) {
    return row * 64 + ((chunk ^ (row & 7)) << 3);
}

// ---------------- init: zero cnt + cnt2 ----------------
__global__ void init_kernel(int* cnt) {
    if (threadIdx.x < 64) cnt[threadIdx.x] = 0;
}

// ---------------- fp32 -> bf16 convert (x) ----------------
__global__ void cvt_kernel(const float* __restrict__ src, unsigned short* __restrict__ dst, int n8) {
    int i = blockIdx.x * blockDim.x + threadIdx.x;
    if (i >= n8) return;
    float4 a = *(const float4*)(src + (size_t)i * 8);
    float4 b = *(const float4*)(src + (size_t)i * 8 + 4);
    u16x8 v;
    v[0] = f2bf(a.x); v[1] = f2bf(a.y); v[2] = f2bf(a.z); v[3] = f2bf(a.w);
    v[4] = f2bf(b.x); v[5] = f2bf(b.y); v[6] = f2bf(b.z); v[7] = f2bf(b.w);
    *(u16x8*)(dst + (size_t)i * 8) = v;
}

// ---------------- gating: 8 tokens per block, fp32 exact ----------------
__global__ __launch_bounds__(256) void gate_kernel(const float* __restrict__ x,
                                                   const float* __restrict__ gw,
                                                   float* __restrict__ logits_out) {
    int tb = blockIdx.x;
    int tid = threadIdx.x;
    __shared__ float xs[GT][H_DIM];          // 32 KB
    __shared__ float ps[8][GT][E_NUM];       // 8 KB
    const float* xsrc = x + (size_t)tb * GT * H_DIM;
    for (int i = tid; i < GT * H_DIM / 4; i += 256)
        ((float4*)&xs[0][0])[i] = ((const float4*)xsrc)[i];
    __syncthreads();
    int e = tid & 31, part = tid >> 5;       // 8 parts x 128 cols
    const float* wrow = gw + (size_t)e * H_DIM + part * 128;
    float acc[GT] = {};
    for (int c0 = 0; c0 < 128; c0 += 32) {
        float w[32];
#pragma unroll
        for (int c = 0; c < 32; c++) w[c] = wrow[c0 + c];
#pragma unroll
        for (int t = 0; t < GT; t++) {
#pragma unroll
            for (int c = 0; c < 32; c++)
                acc[t] += w[c] * xs[t][part * 128 + c0 + c];
        }
    }
#pragma unroll
    for (int t = 0; t < GT; t++) ps[part][t][e] = acc[t];
    __syncthreads();
    {
        int t = tid >> 5, ee = tid & 31;     // 8*32 = 256 exact
        float s = 0.f;
#pragma unroll
        for (int p = 0; p < 8; p++) s += ps[p][t][ee];
        logits_out[((size_t)tb * GT + t) * E_NUM + ee] = s;
    }
}

// ---------------- selection: per-token thread, register-only ----------------
__global__ void select_kernel(const float* __restrict__ logits, const float* __restrict__ gb,
                              int* __restrict__ topk_e, float* __restrict__ topk_w,
                              int* __restrict__ cnt, int T) {
    int t = blockIdx.x * blockDim.x + threadIdx.x;
    if (t >= T) return;
    float scores[E_NUM], sfc[E_NUM];
#pragma unroll
    for (int i = 0; i < E_NUM; i++) {
        float l = logits[(size_t)t * E_NUM + i];
        float s = 1.f / (1.f + expf(-l));
        scores[i] = s;
        sfc[i] = s + gb[i];
    }
    float gs[NGROUP];
#pragma unroll
    for (int g = 0; g < NGROUP; g++) {
        float m1 = -1e30f, m2 = -1e30f;
#pragma unroll
        for (int j = 0; j < 4; j++) {
            float v = sfc[g * 4 + j];
            if (v > m1) { m2 = m1; m1 = v; }
            else if (v > m2) { m2 = v; }
        }
        gs[g] = m1 + m2;
    }
    unsigned gmask = 0;
    for (int r = 0; r < TOPKG; r++) {
        int best = 0; float bv = -1e30f;
#pragma unroll
        for (int g = 0; g < NGROUP; g++)
            if (!((gmask >> g) & 1u) && gs[g] > bv) { bv = gs[g]; best = g; }
        gmask |= 1u << best;
    }
    unsigned cmask = 0;
    int eidx[TOPK]; float ew[TOPK]; float sum = 0.f;
    for (int r = 0; r < TOPK; r++) {
        int best = 0; float bv = -1e30f; float bsc = 0.f;
#pragma unroll
        for (int i = 0; i < E_NUM; i++) {
            float v = ((gmask >> (i >> 2)) & 1u) ? sfc[i] : 0.0f;
            if (!((cmask >> i) & 1u) && v > bv) { bv = v; best = i; bsc = scores[i]; }
        }
        cmask |= 1u << best;
        eidx[r] = best; ew[r] = bsc; sum += bsc;
    }
    float inv = 1.f / (sum + 1e-20f);
#pragma unroll
    for (int k = 0; k < TOPK; k++) {
        topk_e[t * TOPK + k] = eidx[k];
        topk_w[t * TOPK + k] = ew[k] * inv;   // SCALE = 1
        atomicAdd(&cnt[eidx[k]], 1);
    }
}

// ---------------- scan: offsets ----------------
__global__ void scan_kernel(const int* __restrict__ cnt, int* __restrict__ off) {
    if (threadIdx.x == 0) {
        int a = 0;
        for (int e = 0; e < E_NUM; e++) { off[e] = a; a += cnt[e]; }
        off[E_NUM] = a;
    }
}

// ---------------- bin: token -> expert slots ----------------
__global__ void bin_kernel(const int* __restrict__ topk_e, const float* __restrict__ topk_w,
                           const int* __restrict__ off, int* __restrict__ cnt2,
                           int* __restrict__ slot_token, float* __restrict__ slot_w, int total) {
    int i = blockIdx.x * blockDim.x + threadIdx.x;
    if (i >= total) return;
    int e = topk_e[i];
    float w = topk_w[i];
    int pos = atomicAdd(&cnt2[e], 1);
    int slot = off[e] + pos;
    slot_token[slot] = i >> 2;
    slot_w[slot] = w;
}

// ---------------- BM x 64 MFMA GEMM, 512 threads, BK=64, 2-deep reg-prefetch ----------------
// A bf16, B fp32 (converted in-reg). 8 waves: 4 wave-rows x 2 wave-cols.
// ROUTED: blockIdx = (e, itile, mtile)  [expert fastest so live blocks spread over CUs]
// else:   blockIdx = (itile, mtile)
// MODE 0: dst = bf16( silu(g)*u*w )   (DUAL must be true)
// MODE 1: dst(float) = acc            (plain store)
// MODE 2: atomicAdd(out[token], acc)  (routed scatter)
template <int MODE, bool DUAL, int BM, bool ROUTED, bool AGATHER>
__global__ __launch_bounds__(512, 2) void gemm_kernel(
    const unsigned short* __restrict__ A, const float* __restrict__ B1,
    const float* __restrict__ B2, size_t bstride,
    void* __restrict__ Dst, int ldD,
    const int* __restrict__ slot_token, const float* __restrict__ slot_w,
    const int* __restrict__ cnt, const int* __restrict__ off_arr, int K, int Mtot) {
    static_assert(MODE != 0 || DUAL, "MODE0 requires DUAL");
    constexpr int RW = BM / 4;        // rows per wave-row
    constexpr int MF = RW / 16;       // m-frags per wave
    constexpr int ACH = BM / 64;      // A 16B-chunks per thread
    constexpr int TPR = 512 / BM;     // threads per A row

    int itile, mtile, e;
    if constexpr (ROUTED) { e = blockIdx.x; itile = blockIdx.y; mtile = blockIdx.z; }
    else                  { itile = blockIdx.x; mtile = blockIdx.y; e = 0; }
    int count = Mtot, base = 0;
    if (ROUTED) {
        count = cnt[e];
        base = off_arr[e];
        if (mtile * BM >= count) return;
    }

    __shared__ __align__(16) unsigned short As[BM * 64];
    __shared__ __align__(16) unsigned short Bs1[64 * 64];
    __shared__ __align__(16) unsigned short Bs2[DUAL ? 64 * 64 : 8];

    int tid = threadIdx.x;

    // A staging: one row per thread, ACH chunks
    int as_row = tid / TPR;
    int as_cb = (tid % TPR) * ACH;
    int am = mtile * BM + as_row;
    int ar;
    if (AGATHER)      ar = (am < count) ? slot_token[base + am] : 0;
    else if (ROUTED)  ar = base + ((am < count) ? am : 0);
    else              ar = (am < count) ? am : 0;
    const unsigned short* Arow = A + (size_t)ar * K + as_cb * 8;

    // B staging: row = tid>>3, chunk = tid&7 (8 floats each)
    int bs_row = tid >> 3, bs_ch = tid & 7;
    const float* B1r = B1 + (size_t)e * bstride + (size_t)(itile * 64 + bs_row) * K + bs_ch * 8;
    const float* B2r = DUAL ? (B2 + (size_t)e * bstride + (size_t)(itile * 64 + bs_row) * K + bs_ch * 8)
                            : nullptr;

    f32x4 acc1[MF][2] = {};
    f32x4 acc2[DUAL ? MF : 1][2] = {};

    int lane = tid & 63, wid = tid >> 6;
    int wrow = (wid >> 1) * RW, wcol = (wid & 1) * 32;
    int frow = lane & 15, fch = lane >> 4;

    // prefetch register sets (ping-pong, all statically indexed)
    u16x8 pA0[ACH], pA1[ACH];
    float4 b1lo0, b1hi0, b1lo1, b1hi1;
    float4 b2lo0, b2hi0, b2lo1, b2hi1;

    auto loadS = [&](u16x8* pA, float4& b1lo, float4& b1hi, float4& b2lo, float4& b2hi, int k0) {
#pragma unroll
        for (int c = 0; c < ACH; c++) pA[c] = *(const u16x8*)(Arow + k0 + c * 8);
        b1lo = *(const float4*)(B1r + k0);
        b1hi = *(const float4*)(B1r + k0 + 4);
        if constexpr (DUAL) {
            b2lo = *(const float4*)(B2r + k0);
            b2hi = *(const float4*)(B2r + k0 + 4);
        }
    };
    auto writeS = [&](const u16x8* pA, float4 b1lo, float4 b1hi, float4 b2lo, float4 b2hi) {
#pragma unroll
        for (int c = 0; c < ACH; c++)
            *(u16x8*)(&As[laddr(as_row, as_cb + c)]) = pA[c];
        u16x8 s;
        s[0] = f2bf(b1lo.x); s[1] = f2bf(b1lo.y); s[2] = f2bf(b1lo.z); s[3] = f2bf(b1lo.w);
        s[4] = f2bf(b1hi.x); s[5] = f2bf(b1hi.y); s[6] = f2bf(b1hi.z); s[7] = f2bf(b1hi.w);
        *(u16x8*)(&Bs1[laddr(bs_row, bs_ch)]) = s;
        if constexpr (DUAL) {
            u16x8 s2;
            s2[0] = f2bf(b2lo.x); s2[1] = f2bf(b2lo.y); s2[2] = f2bf(b2lo.z); s2[3] = f2bf(b2lo.w);
            s2[4] = f2bf(b2hi.x); s2[5] = f2bf(b2hi.y); s2[6] = f2bf(b2hi.z); s2[7] = f2bf(b2hi.w);
            *(u16x8*)(&Bs2[laddr(bs_row, bs_ch)]) = s2;
        }
    };
    auto compute = [&]() {
#pragma unroll
        for (int kk = 0; kk < 2; kk++) {
            int cb = fch + kk * 4;
            bf16x8 bf1[2], bf2[DUAL ? 2 : 1], af[MF];
#pragma unroll
            for (int nf = 0; nf < 2; nf++)
                bf1[nf] = *(const bf16x8*)(&Bs1[laddr(wcol + nf * 16 + frow, cb)]);
            if constexpr (DUAL) {
#pragma unroll
                for (int nf = 0; nf < 2; nf++)
                    bf2[nf] = *(const bf16x8*)(&Bs2[laddr(wcol + nf * 16 + frow, cb)]);
            }
#pragma unroll
            for (int mf = 0; mf < MF; mf++)
                af[mf] = *(const bf16x8*)(&As[laddr(wrow + mf * 16 + frow, cb)]);
#pragma unroll
            for (int mf = 0; mf < MF; mf++)
#pragma unroll
                for (int nf = 0; nf < 2; nf++) {
                    acc1[mf][nf] = __builtin_amdgcn_mfma_f32_16x16x32_bf16(af[mf], bf1[nf], acc1[mf][nf], 0, 0, 0);
                    if constexpr (DUAL)
                        acc2[mf][nf] = __builtin_amdgcn_mfma_f32_16x16x32_bf16(af[mf], bf2[nf], acc2[mf][nf], 0, 0, 0);
                }
        }
    };

    const int NK = K >> 6;   // even for all uses (16, 16, 16, 8)
    loadS(pA0, b1lo0, b1hi0, b2lo0, b2hi0, 0);
    loadS(pA1, b1lo1, b1hi1, b2lo1, b2hi1, 64);
    for (int it = 0; it < NK; it += 2) {
        __syncthreads();                           // prev compute done reading LDS
        writeS(pA0, b1lo0, b1hi0, b2lo0, b2hi0);   // set0 issued ~2 phases ago: no stall
        __syncthreads();                           // LDS ready
        if (it + 2 < NK) loadS(pA0, b1lo0, b1hi0, b2lo0, b2hi0, (it + 2) << 6);
        compute();
        __syncthreads();
        writeS(pA1, b1lo1, b1hi1, b2lo1, b2hi1);
        __syncthreads();
        if (it + 3 < NK) loadS(pA1, b1lo1, b1hi1, b2lo1, b2hi1, (it + 3) << 6);
        compute();
    }

    // ---- epilogue ----
#pragma unroll
    for (int mf = 0; mf < MF; mf++)
#pragma unroll
        for (int nf = 0; nf < 2; nf++)
#pragma unroll
            for (int j = 0; j < 4; j++) {
                int rloc = wrow + mf * 16 + (lane >> 4) * 4 + j;
                int mrow = mtile * BM + rloc;
                int col = itile * 64 + wcol + nf * 16 + (lane & 15);
                if (mrow >= count) continue;
                if constexpr (MODE == 0) {
                    float w = ROUTED ? slot_w[base + mrow] : 1.0f;
                    float g = acc1[mf][nf][j];
                    float a = (g / (1.f + __expf(-g))) * acc2[mf][nf][j] * w;
                    ((unsigned short*)Dst)[(size_t)(base + mrow) * ldD + col] = f2bf(a);
                } else if constexpr (MODE == 1) {
                    ((float*)Dst)[(size_t)mrow * ldD + col] = acc1[mf][nf][j];
                } else {
                    int tok = slot_token[base + mrow];
                    atomicAdd(((float*)Dst) + (size_t)tok * ldD + col, acc1[mf][nf][j]);
                }
            }
}

extern "C" void kernel_launch(void* const* d_in, const int* in_sizes, int n_in,
                              void* d_out, int out_size, void* d_ws, size_t ws_size,
                              hipStream_t stream) {
    const float* x = (const float*)d_in[0];
    const float* gw = (const float*)d_in[1];
    const float* gb = (const float*)d_in[2];
    const float* gate_proj = (const float*)d_in[3];
    const float* up_proj = (const float*)d_in[4];
    const float* down_proj = (const float*)d_in[5];
    const float* sgw = (const float*)d_in[6];
    const float* suw = (const float*)d_in[7];
    const float* sdw = (const float*)d_in[8];
    float* out = (float*)d_out;

    const int T = in_sizes[0] / H_DIM;       // 2048
    const int total_slots = T * TOPK;        // 8192

    char* ws = (char*)d_ws;
    int* cnt = (int*)ws;                     // 32
    int* cnt2 = cnt + 32;                    // 32
    int* off = cnt + 64;                     // 33
    int* topk_e = cnt + 128;
    float* topk_w = (float*)(topk_e + total_slots);
    int* slot_token = (int*)(topk_w + total_slots);
    float* slot_w = (float*)(slot_token + total_slots);
    float* logits = slot_w + total_slots;                         // T*32 f32
    unsigned short* x_bf = (unsigned short*)(logits + (size_t)T * E_NUM);
    unsigned short* act_r = x_bf + (size_t)T * H_DIM;             // (slots+256) x I
    unsigned short* act_s = act_r + (size_t)(total_slots + 256) * I_DIM;  // T x SHARED_I

    hipLaunchKernelGGL(init_kernel, dim3(1), dim3(64), 0, stream, cnt);
    hipLaunchKernelGGL(cvt_kernel, dim3((T * H_DIM / 8 + 255) / 256), dim3(256), 0, stream,
                       x, x_bf, T * H_DIM / 8);
    hipLaunchKernelGGL(gate_kernel, dim3(T / GT), dim3(256), 0, stream, x, gw, logits);
    hipLaunchKernelGGL(select_kernel, dim3((T + 255) / 256), dim3(256), 0, stream,
                       logits, gb, topk_e, topk_w, cnt, T);
    hipLaunchKernelGGL(scan_kernel, dim3(1), dim3(1), 0, stream, cnt, off);
    hipLaunchKernelGGL(bin_kernel, dim3((total_slots + 255) / 256), dim3(256), 0, stream,
                       topk_e, topk_w, off, cnt2, slot_token, slot_w, total_slots);

    // routed stage 1: BM=256 (weights read once); expert index FASTEST in grid
    hipLaunchKernelGGL((gemm_kernel<0, true, 256, true, true>),
                       dim3(E_NUM, I_DIM / 64, 32), dim3(512), 0, stream,
                       x_bf, gate_proj, up_proj, (size_t)I_DIM * H_DIM,
                       (void*)act_r, I_DIM, slot_token, slot_w, cnt, off, H_DIM, 0);

    // shared stage 1: BM=128, 128 blocks all live
    hipLaunchKernelGGL((gemm_kernel<0, true, 128, false, false>),
                       dim3(SHARED_I_DIM / 64, T / 128, 1), dim3(512), 0, stream,
                       x_bf, sgw, suw, (size_t)0,
                       (void*)act_s, SHARED_I_DIM, (const int*)nullptr, (const float*)nullptr,
                       (const int*)nullptr, (const int*)nullptr, H_DIM, T);

    // shared down: plain fp32 store (covers every (t,h) once)
    hipLaunchKernelGGL((gemm_kernel<1, false, 128, false, false>),
                       dim3(H_DIM / 64, T / 128, 1), dim3(512), 0, stream,
                       act_s, sdw, (const float*)nullptr, (size_t)0,
                       (void*)out, H_DIM, (const int*)nullptr, (const float*)nullptr,
                       (const int*)nullptr, (const int*)nullptr, SHARED_I_DIM, T);

    // routed down: BM=256, atomicAdd scatter; expert index FASTEST in grid
    hipLaunchKernelGGL((gemm_kernel<2, false, 256, true, false>),
                       dim3(E_NUM, H_DIM / 64, 32), dim3(512), 0, stream,
                       act_r, down_proj, (const float*)nullptr, (size_t)H_DIM * I_DIM,
                       (void*)out, H_DIM, slot_token, (const float*)nullptr, cnt, off, I_DIM, 0);
}

// Round 6
// 204.474 us; speedup vs baseline: 2.0579x; 1.1226x over previous
//
#include <hip/hip_runtime.h>
#include <hip/hip_bf16.h>
#include <cstdint>
#include <cstddef>

#define H_DIM 1024
#define I_DIM 512
#define E_NUM 32
#define SHARED_I_DIM 1024
#define TOPK 4
#define NGROUP 8
#define TOPKG 4
#define GT 8   // tokens per gate block

typedef __attribute__((ext_vector_type(8))) short bf16x8;
typedef __attribute__((ext_vector_type(4))) float f32x4;
typedef __attribute__((ext_vector_type(8))) unsigned short u16x8;

__device__ inline unsigned short f2bf(float f) {
    __hip_bfloat16 h = __float2bfloat16(f);   // RNE -> v_cvt_pk_bf16_f32
    return *reinterpret_cast<unsigned short*>(&h);
}
__device__ inline float bf2f(unsigned short u) {
    union { unsigned int u; float f; } w;
    w.u = ((unsigned int)u) << 16;
    return w.f;
}

// LDS address (in shorts) for [rows][64] bf16 tile, 16B-chunk XOR swizzle.
__device__ inline int laddr(int row, int chunk) {
    return row * 64 + ((chunk ^ (row & 7)) << 3);
}

// ---------------- init: zero cnt + cnt2 ----------------
__global__ void init_kernel(int* cnt) {
    if (threadIdx.x < 64) cnt[threadIdx.x] = 0;
}

// ---------------- fp32 -> bf16 convert (x) ----------------
__global__ void cvt_kernel(const float* __restrict__ src, unsigned short* __restrict__ dst, int n8) {
    int i = blockIdx.x * blockDim.x + threadIdx.x;
    if (i >= n8) return;
    float4 a = *(const float4*)(src + (size_t)i * 8);
    float4 b = *(const float4*)(src + (size_t)i * 8 + 4);
    u16x8 v;
    v[0] = f2bf(a.x); v[1] = f2bf(a.y); v[2] = f2bf(a.z); v[3] = f2bf(a.w);
    v[4] = f2bf(b.x); v[5] = f2bf(b.y); v[6] = f2bf(b.z); v[7] = f2bf(b.w);
    *(u16x8*)(dst + (size_t)i * 8) = v;
}

// ---------------- gating: 8 tokens per block, fp32 exact ----------------
__global__ __launch_bounds__(256) void gate_kernel(const float* __restrict__ x,
                                                   const float* __restrict__ gw,
                                                   float* __restrict__ logits_out) {
    int tb = blockIdx.x;
    int tid = threadIdx.x;
    __shared__ float xs[GT][H_DIM];          // 32 KB
    __shared__ float ps[8][GT][E_NUM];       // 8 KB
    const float* xsrc = x + (size_t)tb * GT * H_DIM;
    for (int i = tid; i < GT * H_DIM / 4; i += 256)
        ((float4*)&xs[0][0])[i] = ((const float4*)xsrc)[i];
    __syncthreads();
    int e = tid & 31, part = tid >> 5;       // 8 parts x 128 cols
    const float* wrow = gw + (size_t)e * H_DIM + part * 128;
    float acc[GT] = {};
    for (int c0 = 0; c0 < 128; c0 += 32) {
        float w[32];
#pragma unroll
        for (int c = 0; c < 32; c++) w[c] = wrow[c0 + c];
#pragma unroll
        for (int t = 0; t < GT; t++) {
#pragma unroll
            for (int c = 0; c < 32; c++)
                acc[t] += w[c] * xs[t][part * 128 + c0 + c];
        }
    }
#pragma unroll
    for (int t = 0; t < GT; t++) ps[part][t][e] = acc[t];
    __syncthreads();
    {
        int t = tid >> 5, ee = tid & 31;     // 8*32 = 256 exact
        float s = 0.f;
#pragma unroll
        for (int p = 0; p < 8; p++) s += ps[p][t][ee];
        logits_out[((size_t)tb * GT + t) * E_NUM + ee] = s;
    }
}

// ---------------- selection: per-token thread, register-only ----------------
__global__ void select_kernel(const float* __restrict__ logits, const float* __restrict__ gb,
                              int* __restrict__ topk_e, float* __restrict__ topk_w,
                              int* __restrict__ cnt, int T) {
    int t = blockIdx.x * blockDim.x + threadIdx.x;
    if (t >= T) return;
    float scores[E_NUM], sfc[E_NUM];
#pragma unroll
    for (int i = 0; i < E_NUM; i++) {
        float l = logits[(size_t)t * E_NUM + i];
        float s = 1.f / (1.f + expf(-l));
        scores[i] = s;
        sfc[i] = s + gb[i];
    }
    float gs[NGROUP];
#pragma unroll
    for (int g = 0; g < NGROUP; g++) {
        float m1 = -1e30f, m2 = -1e30f;
#pragma unroll
        for (int j = 0; j < 4; j++) {
            float v = sfc[g * 4 + j];
            if (v > m1) { m2 = m1; m1 = v; }
            else if (v > m2) { m2 = v; }
        }
        gs[g] = m1 + m2;
    }
    unsigned gmask = 0;
    for (int r = 0; r < TOPKG; r++) {
        int best = 0; float bv = -1e30f;
#pragma unroll
        for (int g = 0; g < NGROUP; g++)
            if (!((gmask >> g) & 1u) && gs[g] > bv) { bv = gs[g]; best = g; }
        gmask |= 1u << best;
    }
    unsigned cmask = 0;
    int eidx[TOPK]; float ew[TOPK]; float sum = 0.f;
    for (int r = 0; r < TOPK; r++) {
        int best = 0; float bv = -1e30f; float bsc = 0.f;
#pragma unroll
        for (int i = 0; i < E_NUM; i++) {
            float v = ((gmask >> (i >> 2)) & 1u) ? sfc[i] : 0.0f;
            if (!((cmask >> i) & 1u) && v > bv) { bv = v; best = i; bsc = scores[i]; }
        }
        cmask |= 1u << best;
        eidx[r] = best; ew[r] = bsc; sum += bsc;
    }
    float inv = 1.f / (sum + 1e-20f);
#pragma unroll
    for (int k = 0; k < TOPK; k++) {
        topk_e[t * TOPK + k] = eidx[k];
        topk_w[t * TOPK + k] = ew[k] * inv;   // SCALE = 1
        atomicAdd(&cnt[eidx[k]], 1);
    }
}

// ---------------- scan: offsets ----------------
__global__ void scan_kernel(const int* __restrict__ cnt, int* __restrict__ off) {
    if (threadIdx.x == 0) {
        int a = 0;
        for (int e = 0; e < E_NUM; e++) { off[e] = a; a += cnt[e]; }
        off[E_NUM] = a;
    }
}

// ---------------- bin: token -> expert slots (+ inverse map) ----------------
__global__ void bin_kernel(const int* __restrict__ topk_e, const float* __restrict__ topk_w,
                           const int* __restrict__ off, int* __restrict__ cnt2,
                           int* __restrict__ slot_token, float* __restrict__ slot_w,
                           int* __restrict__ slot_of, int total) {
    int i = blockIdx.x * blockDim.x + threadIdx.x;
    if (i >= total) return;
    int e = topk_e[i];
    float w = topk_w[i];
    int pos = atomicAdd(&cnt2[e], 1);
    int slot = off[e] + pos;
    slot_token[slot] = i >> 2;
    slot_w[slot] = w;
    slot_of[i] = slot;
}

// ---------------- combine: out[t] += sum of 4 routed slot rows ----------------
__global__ __launch_bounds__(256) void combine_kernel(const unsigned short* __restrict__ out_slot,
                                                      const int* __restrict__ slot_of,
                                                      float* __restrict__ out) {
    int t = blockIdx.x;
    int h = threadIdx.x * 4;                 // 256 * 4 = 1024
    int s0 = slot_of[t * TOPK + 0], s1 = slot_of[t * TOPK + 1];
    int s2 = slot_of[t * TOPK + 2], s3 = slot_of[t * TOPK + 3];
    ushort4 a = *(const ushort4*)(out_slot + (size_t)s0 * H_DIM + h);
    ushort4 b = *(const ushort4*)(out_slot + (size_t)s1 * H_DIM + h);
    ushort4 c = *(const ushort4*)(out_slot + (size_t)s2 * H_DIM + h);
    ushort4 d = *(const ushort4*)(out_slot + (size_t)s3 * H_DIM + h);
    float4 o = *(float4*)(out + (size_t)t * H_DIM + h);
    o.x += bf2f(a.x) + bf2f(b.x) + bf2f(c.x) + bf2f(d.x);
    o.y += bf2f(a.y) + bf2f(b.y) + bf2f(c.y) + bf2f(d.y);
    o.z += bf2f(a.z) + bf2f(b.z) + bf2f(c.z) + bf2f(d.z);
    o.w += bf2f(a.w) + bf2f(b.w) + bf2f(c.w) + bf2f(d.w);
    *(float4*)(out + (size_t)t * H_DIM + h) = o;
}

// ---------------- BM x 64 MFMA GEMM, 512 threads, BK=64 ----------------
// LDS double-buffered (1 barrier / K-step) + 2-deep register prefetch.
// A bf16, B fp32 (converted in-reg). 8 waves: 4 wave-rows x 2 wave-cols.
// ROUTED: blockIdx = (e, itile, mtile)  [expert fastest: live blocks spread over CUs]
// MODE 0: dst = bf16( silu(g)*u*w )   (DUAL must be true)
// MODE 1: dst(float) = acc            (plain store)
// MODE 3: dst = bf16(acc) at slot row (plain store, no atomics)
template <int MODE, bool DUAL, int BM, bool ROUTED, bool AGATHER>
__global__ __launch_bounds__(512, 2) void gemm_kernel(
    const unsigned short* __restrict__ A, const float* __restrict__ B1,
    const float* __restrict__ B2, size_t bstride,
    void* __restrict__ Dst, int ldD,
    const int* __restrict__ slot_token, const float* __restrict__ slot_w,
    const int* __restrict__ cnt, const int* __restrict__ off_arr, int K, int Mtot) {
    static_assert(MODE != 0 || DUAL, "MODE0 requires DUAL");
    constexpr int RW = BM / 4;        // rows per wave-row
    constexpr int MF = RW / 16;       // m-frags per wave
    constexpr int ACH = BM / 64;      // A 16B-chunks per thread
    constexpr int TPR = 512 / BM;     // threads per A row

    int itile, mtile, e;
    if constexpr (ROUTED) { e = blockIdx.x; itile = blockIdx.y; mtile = blockIdx.z; }
    else                  { itile = blockIdx.x; mtile = blockIdx.y; e = 0; }
    int count = Mtot, base = 0;
    if (ROUTED) {
        count = cnt[e];
        base = off_arr[e];
        if (mtile * BM >= count) return;
    }

    __shared__ __align__(16) unsigned short As[2][BM * 64];
    __shared__ __align__(16) unsigned short Bs1[2][64 * 64];
    __shared__ __align__(16) unsigned short Bs2[2][DUAL ? 64 * 64 : 8];

    int tid = threadIdx.x;

    // A staging: one row per thread, ACH chunks
    int as_row = tid / TPR;
    int as_cb = (tid % TPR) * ACH;
    int am = mtile * BM + as_row;
    int ar;
    if (AGATHER)      ar = (am < count) ? slot_token[base + am] : 0;
    else if (ROUTED)  ar = base + ((am < count) ? am : 0);
    else              ar = (am < count) ? am : 0;
    const unsigned short* Arow = A + (size_t)ar * K + as_cb * 8;

    // B staging: row = tid>>3, chunk = tid&7 (8 floats each)
    int bs_row = tid >> 3, bs_ch = tid & 7;
    const float* B1r = B1 + (size_t)e * bstride + (size_t)(itile * 64 + bs_row) * K + bs_ch * 8;
    const float* B2r = DUAL ? (B2 + (size_t)e * bstride + (size_t)(itile * 64 + bs_row) * K + bs_ch * 8)
                            : nullptr;

    f32x4 acc1[MF][2] = {};
    f32x4 acc2[DUAL ? MF : 1][2] = {};

    int lane = tid & 63, wid = tid >> 6;
    int wrow = (wid >> 1) * RW, wcol = (wid & 1) * 32;
    int frow = lane & 15, fch = lane >> 4;

    // prefetch register sets (ping-pong, all statically indexed)
    u16x8 pA0[ACH], pA1[ACH];
    float4 b1lo0, b1hi0, b1lo1, b1hi1;
    float4 b2lo0, b2hi0, b2lo1, b2hi1;

    auto loadS = [&](u16x8* pA, float4& b1lo, float4& b1hi, float4& b2lo, float4& b2hi, int k0) {
#pragma unroll
        for (int c = 0; c < ACH; c++) pA[c] = *(const u16x8*)(Arow + k0 + c * 8);
        b1lo = *(const float4*)(B1r + k0);
        b1hi = *(const float4*)(B1r + k0 + 4);
        if constexpr (DUAL) {
            b2lo = *(const float4*)(B2r + k0);
            b2hi = *(const float4*)(B2r + k0 + 4);
        }
    };
    auto writeS = [&](int buf, const u16x8* pA, float4 b1lo, float4 b1hi, float4 b2lo, float4 b2hi) {
        unsigned short* As_ = As[buf];
        unsigned short* Bs1_ = Bs1[buf];
#pragma unroll
        for (int c = 0; c < ACH; c++)
            *(u16x8*)(&As_[laddr(as_row, as_cb + c)]) = pA[c];
        u16x8 s;
        s[0] = f2bf(b1lo.x); s[1] = f2bf(b1lo.y); s[2] = f2bf(b1lo.z); s[3] = f2bf(b1lo.w);
        s[4] = f2bf(b1hi.x); s[5] = f2bf(b1hi.y); s[6] = f2bf(b1hi.z); s[7] = f2bf(b1hi.w);
        *(u16x8*)(&Bs1_[laddr(bs_row, bs_ch)]) = s;
        if constexpr (DUAL) {
            unsigned short* Bs2_ = Bs2[buf];
            u16x8 s2;
            s2[0] = f2bf(b2lo.x); s2[1] = f2bf(b2lo.y); s2[2] = f2bf(b2lo.z); s2[3] = f2bf(b2lo.w);
            s2[4] = f2bf(b2hi.x); s2[5] = f2bf(b2hi.y); s2[6] = f2bf(b2hi.z); s2[7] = f2bf(b2hi.w);
            *(u16x8*)(&Bs2_[laddr(bs_row, bs_ch)]) = s2;
        }
    };
    auto compute = [&](int buf) {
        const unsigned short* As_ = As[buf];
        const unsigned short* Bs1_ = Bs1[buf];
        const unsigned short* Bs2_ = Bs2[buf];
#pragma unroll
        for (int kk = 0; kk < 2; kk++) {
            int cb = fch + kk * 4;
            bf16x8 bf1[2], bf2[DUAL ? 2 : 1], af[MF];
#pragma unroll
            for (int nf = 0; nf < 2; nf++)
                bf1[nf] = *(const bf16x8*)(&Bs1_[laddr(wcol + nf * 16 + frow, cb)]);
            if constexpr (DUAL) {
#pragma unroll
                for (int nf = 0; nf < 2; nf++)
                    bf2[nf] = *(const bf16x8*)(&Bs2_[laddr(wcol + nf * 16 + frow, cb)]);
            }
#pragma unroll
            for (int mf = 0; mf < MF; mf++)
                af[mf] = *(const bf16x8*)(&As_[laddr(wrow + mf * 16 + frow, cb)]);
#pragma unroll
            for (int mf = 0; mf < MF; mf++)
#pragma unroll
                for (int nf = 0; nf < 2; nf++) {
                    acc1[mf][nf] = __builtin_amdgcn_mfma_f32_16x16x32_bf16(af[mf], bf1[nf], acc1[mf][nf], 0, 0, 0);
                    if constexpr (DUAL)
                        acc2[mf][nf] = __builtin_amdgcn_mfma_f32_16x16x32_bf16(af[mf], bf2[nf], acc2[mf][nf], 0, 0, 0);
                }
        }
    };

    const int NK = K >> 6;   // 16, 16, 16, or 8 (always even, >= 8)
    // prologue: fill buf0, prefetch sets for k=1 (buf1) and k=2 (buf0)
    loadS(pA0, b1lo0, b1hi0, b2lo0, b2hi0, 0);
    loadS(pA1, b1lo1, b1hi1, b2lo1, b2hi1, 64);
    writeS(0, pA0, b1lo0, b1hi0, b2lo0, b2hi0);
    loadS(pA0, b1lo0, b1hi0, b2lo0, b2hi0, 128);
    __syncthreads();                               // buf0 ready
    for (int it = 0; it < NK; it += 2) {
        // step it: compute buf0 (k=it), stage buf1 (k=it+1)
        writeS(1, pA1, b1lo1, b1hi1, b2lo1, b2hi1);
        if (it + 3 < NK) loadS(pA1, b1lo1, b1hi1, b2lo1, b2hi1, (it + 3) << 6);
        compute(0);
        __syncthreads();                           // buf1 ready, buf0 free
        // step it+1: compute buf1 (k=it+1), stage buf0 (k=it+2)
        if (it + 2 < NK) {
            writeS(0, pA0, b1lo0, b1hi0, b2lo0, b2hi0);
            if (it + 4 < NK) loadS(pA0, b1lo0, b1hi0, b2lo0, b2hi0, (it + 4) << 6);
        }
        compute(1);
        if (it + 2 < NK) __syncthreads();          // buf0 ready, buf1 free
    }

    // ---- epilogue ----
#pragma unroll
    for (int mf = 0; mf < MF; mf++)
#pragma unroll
        for (int nf = 0; nf < 2; nf++)
#pragma unroll
            for (int j = 0; j < 4; j++) {
                int rloc = wrow + mf * 16 + (lane >> 4) * 4 + j;
                int mrow = mtile * BM + rloc;
                int col = itile * 64 + wcol + nf * 16 + (lane & 15);
                if (mrow >= count) continue;
                if constexpr (MODE == 0) {
                    float w = ROUTED ? slot_w[base + mrow] : 1.0f;
                    float g = acc1[mf][nf][j];
                    float a = (g / (1.f + __expf(-g))) * acc2[mf][nf][j] * w;
                    ((unsigned short*)Dst)[(size_t)(base + mrow) * ldD + col] = f2bf(a);
                } else if constexpr (MODE == 1) {
                    ((float*)Dst)[(size_t)mrow * ldD + col] = acc1[mf][nf][j];
                } else {  // MODE 3: plain bf16 store at slot row
                    ((unsigned short*)Dst)[(size_t)(base + mrow) * ldD + col] = f2bf(acc1[mf][nf][j]);
                }
            }
}

extern "C" void kernel_launch(void* const* d_in, const int* in_sizes, int n_in,
                              void* d_out, int out_size, void* d_ws, size_t ws_size,
                              hipStream_t stream) {
    const float* x = (const float*)d_in[0];
    const float* gw = (const float*)d_in[1];
    const float* gb = (const float*)d_in[2];
    const float* gate_proj = (const float*)d_in[3];
    const float* up_proj = (const float*)d_in[4];
    const float* down_proj = (const float*)d_in[5];
    const float* sgw = (const float*)d_in[6];
    const float* suw = (const float*)d_in[7];
    const float* sdw = (const float*)d_in[8];
    float* out = (float*)d_out;

    const int T = in_sizes[0] / H_DIM;       // 2048
    const int total_slots = T * TOPK;        // 8192

    char* ws = (char*)d_ws;
    int* cnt = (int*)ws;                     // 32
    int* cnt2 = cnt + 32;                    // 32
    int* off = cnt + 64;                     // 33
    int* topk_e = cnt + 128;
    float* topk_w = (float*)(topk_e + total_slots);
    int* slot_token = (int*)(topk_w + total_slots);
    float* slot_w = (float*)(slot_token + total_slots);
    int* slot_of = (int*)(slot_w + total_slots);
    float* logits = (float*)(slot_of + total_slots);              // T*32 f32
    unsigned short* x_bf = (unsigned short*)(logits + (size_t)T * E_NUM);
    unsigned short* act_r = x_bf + (size_t)T * H_DIM;             // (slots+256) x I
    unsigned short* act_s = act_r + (size_t)(total_slots + 256) * I_DIM;   // T x SHARED_I
    unsigned short* out_slot = act_s + (size_t)T * SHARED_I_DIM;  // (slots+256) x H

    hipLaunchKernelGGL(init_kernel, dim3(1), dim3(64), 0, stream, cnt);
    hipLaunchKernelGGL(cvt_kernel, dim3((T * H_DIM / 8 + 255) / 256), dim3(256), 0, stream,
                       x, x_bf, T * H_DIM / 8);
    hipLaunchKernelGGL(gate_kernel, dim3(T / GT), dim3(256), 0, stream, x, gw, logits);
    hipLaunchKernelGGL(select_kernel, dim3((T + 255) / 256), dim3(256), 0, stream,
                       logits, gb, topk_e, topk_w, cnt, T);
    hipLaunchKernelGGL(scan_kernel, dim3(1), dim3(1), 0, stream, cnt, off);
    hipLaunchKernelGGL(bin_kernel, dim3((total_slots + 255) / 256), dim3(256), 0, stream,
                       topk_e, topk_w, off, cnt2, slot_token, slot_w, slot_of, total_slots);

    // routed stage 1: BM=256 (weights read once); expert index fastest in grid
    hipLaunchKernelGGL((gemm_kernel<0, true, 256, true, true>),
                       dim3(E_NUM, I_DIM / 64, 32), dim3(512), 0, stream,
                       x_bf, gate_proj, up_proj, (size_t)I_DIM * H_DIM,
                       (void*)act_r, I_DIM, slot_token, slot_w, cnt, off, H_DIM, 0);

    // shared stage 1: BM=128
    hipLaunchKernelGGL((gemm_kernel<0, true, 128, false, false>),
                       dim3(SHARED_I_DIM / 64, T / 128, 1), dim3(512), 0, stream,
                       x_bf, sgw, suw, (size_t)0,
                       (void*)act_s, SHARED_I_DIM, (const int*)nullptr, (const float*)nullptr,
                       (const int*)nullptr, (const int*)nullptr, H_DIM, T);

    // shared down: plain fp32 store (covers every (t,h) once)
    hipLaunchKernelGGL((gemm_kernel<1, false, 128, false, false>),
                       dim3(H_DIM / 64, T / 128, 1), dim3(512), 0, stream,
                       act_s, sdw, (const float*)nullptr, (size_t)0,
                       (void*)out, H_DIM, (const int*)nullptr, (const float*)nullptr,
                       (const int*)nullptr, (const int*)nullptr, SHARED_I_DIM, T);

    // routed down: BM=256, bf16 slot-row store (no atomics); expert index fastest
    hipLaunchKernelGGL((gemm_kernel<3, false, 256, true, false>),
                       dim3(E_NUM, H_DIM / 64, 32), dim3(512), 0, stream,
                       act_r, down_proj, (const float*)nullptr, (size_t)H_DIM * I_DIM,
                       (void*)out_slot, H_DIM, slot_token, (const float*)nullptr, cnt, off, I_DIM, 0);

    // combine: out[t] += sum of the token's 4 routed slot rows
    hipLaunchKernelGGL(combine_kernel, dim3(T), dim3(256), 0, stream, out_slot, slot_of, out);
}